// Round 6
// baseline (195.775 us; speedup 1.0000x reference)
//
#include <hip/hip_runtime.h>

#define NROIS 1024
#define BANDS 7
#define M_TOT (NROIS*BANDS)        // 7168
#define ROI_W 224
#define BAND_H 16
#define FLATD 512
#define HD 1024                     // 8 heads * 128
#define PROV 38
#define ALPHA 25
#define ADC 35
#define NAD 6

#define OFF_A     (M_TOT*PROV)               // 272384
#define OFF_AD    (OFF_A + M_TOT*ALPHA)      // 451584
#define OFF_MASK  (OFF_AD + NAD*M_TOT*ADC)   // 1956864
#define OFF_TOTAL (OFF_MASK + M_TOT)         // 1964032

typedef __attribute__((ext_vector_type(4))) float f32x4;
typedef __attribute__((ext_vector_type(8))) short bf16x8;

static __device__ __forceinline__ unsigned short f2bf(float f){
    union { float f; unsigned int u; } v; v.f = f;
    unsigned int u = v.u;
    unsigned int r = (u + 0x7fffu + ((u >> 16) & 1u)) >> 16;
    return (unsigned short)r;
}

// P[c][r][j] = max over x[c][r..r+1][j..j+13];  r in [0,1023), j in [0,1011)
#define PIDX(c,r,j) (((size_t)(c)*1023 + (r))*1024 + (j))

// ---------------- Kernel 0: precompute sliding 2x14 max P
__global__ __launch_bounds__(256) void k_precompute(
    const float* __restrict__ x, float* __restrict__ P)
{
    __shared__ float v[1024];
    int blk = blockIdx.x;
    int c = blk / 1023, r = blk - c*1023;
    int t = threadIdx.x;
    const float* row0 = x + ((size_t)c*1024 + r)*1024;
    const float* row1 = row0 + 1024;
    #pragma unroll
    for (int i=0;i<4;i++){
        int j = t + i*256;
        v[j] = fmaxf(row0[j], row1[j]);
    }
    __syncthreads();
    float* Pr = P + PIDX(c, r, 0);
    #pragma unroll
    for (int i=0;i<4;i++){
        int j = t + i*256;
        if (j < 1011){
            float mv = v[j];
            #pragma unroll
            for (int d=1;d<14;d++) mv = fmaxf(mv, v[j+d]);
            Pr[j] = mv;
        }
    }
}

// ---------------- Kernel 1: gather pooled from P -> conv (reg-weights) -> relu -> 2x2 maxpool -> flat bf16
__global__ __launch_bounds__(256) void k_extract(
    const float* __restrict__ P, const int* __restrict__ rois,
    const float* __restrict__ conv_w, const float* __restrict__ conv_b,
    unsigned short* __restrict__ flat)
{
    __shared__ float pl[3][10][18];
    __shared__ float cw[432];
    __shared__ float cb[16];

    int blk = blockIdx.x;
    int r = blk / BANDS, b = blk - r*BANDS;
    int xx = rois[r*4+0];
    int yy = rois[r*4+1] + b*BAND_H;
    int t = threadIdx.x;

    for (int i=t;i<432;i+=256) cw[i]=conv_w[i];
    if (t<16) cb[t]=conv_b[t];
    for (int i=t;i<3*10*18;i+=256) ((float*)pl)[i]=0.f;
    __syncthreads();

    for (int idx=t; idx<384; idx+=256){
        int c = idx>>7; int rem = idx&127; int ph = rem>>4; int pw = rem&15;
        pl[c][ph+1][pw+1] = P[PIDX(c, yy + 2*ph, xx + 14*pw)];
    }
    __syncthreads();

    #pragma unroll
    for (int pass=0; pass<2; pass++){
        int f = t + pass*256;
        int o = f>>5, p=(f>>3)&3, q=f&7;
        float bias = cb[o];
        float s00=bias, s01=bias, s10=bias, s11=bias;
        #pragma unroll
        for (int c=0;c<3;c++){
            float w[9];
            #pragma unroll
            for (int k=0;k<9;k++) w[k] = cw[(o*3+c)*9 + k];
            float pt[4][4];
            #pragma unroll
            for (int di=0; di<4; di++)
              #pragma unroll
              for (int dj=0; dj<4; dj++)
                pt[di][dj] = pl[c][2*p+di][2*q+dj];
            #pragma unroll
            for (int kh=0;kh<3;kh++)
              #pragma unroll
              for (int kw=0;kw<3;kw++){
                float ww = w[kh*3+kw];
                s00 += pt[kh  ][kw  ]*ww;
                s01 += pt[kh  ][kw+1]*ww;
                s10 += pt[kh+1][kw  ]*ww;
                s11 += pt[kh+1][kw+1]*ww;
              }
        }
        float mx = fmaxf(fmaxf(fmaxf(s00,s01), fmaxf(s10,s11)), 0.f);
        flat[(size_t)blk*512 + f] = f2bf(mx);
    }
}

// ---------------- Kernel 1b: all weight conversions in one launch
// i < 524288: w1 -> Bt[n][k] bf16 ; else w2* -> B2[8][48][128] bf16 + bias2[8][48]
__global__ __launch_bounds__(256) void k_cvt(
    const float* __restrict__ w1,
    const float* __restrict__ w2p, const float* __restrict__ b2p,
    const float* __restrict__ w2a, const float* __restrict__ b2a,
    const float* __restrict__ w2ad, const float* __restrict__ b2ad,
    unsigned short* __restrict__ Bt, unsigned short* __restrict__ B2,
    float* __restrict__ bias2)
{
    int i = blockIdx.x*256 + threadIdx.x;
    if (i < 524288){
        int k = i >> 10, n = i & 1023;
        float v = w1[((size_t)(n>>7)*512 + k)*128 + (n&127)];
        Bt[(size_t)n*512 + k] = f2bf(v);
    } else {
        int j = i - 524288;          // < 49152
        int h = j / 6144;
        int rem = j - h*6144;
        int n = rem >> 7, k = rem & 127;
        float v = 0.f;
        if (h == 0){ if (n < 38) v = w2p[k*38 + n]; }
        else if (h == 1){ if (n < 25) v = w2a[k*25 + n]; }
        else { if (n < 35) v = w2ad[(size_t)(h-2)*128*35 + k*35 + n]; }
        B2[j] = f2bf(v);
        if (j < 8*48){
            int hh = j / 48, nn = j - hh*48;
            float bv = 0.f;
            if (hh == 0){ if (nn < 38) bv = b2p[nn]; }
            else if (hh == 1){ if (nn < 25) bv = b2a[nn]; }
            else { if (nn < 35) bv = b2ad[(hh-2)*35 + nn]; }
            bias2[j] = bv;
        }
    }
}

// ---------------- Kernel 2: H = relu(flat @ W1cat + b1cat), LDS-free direct-global MFMA
// grid (28 m-tiles of 256, 16 n-tiles of 64); wave w owns rows w*64..+63; acc 4x4 fragments
__global__ __launch_bounds__(256) void k_fc1_mfma(
    const unsigned short* __restrict__ A, const unsigned short* __restrict__ Bt,
    const float* __restrict__ b1, unsigned short* __restrict__ H)
{
    int bm = blockIdx.x, bn = blockIdx.y;
    int t = threadIdx.x;
    int wid = t >> 6, lane = t & 63;
    int l15 = lane & 15, l4 = lane >> 4;

    f32x4 acc[4][4];
    #pragma unroll
    for (int i=0;i<4;i++)
      #pragma unroll
      for (int j=0;j<4;j++) acc[i][j] = (f32x4){0.f,0.f,0.f,0.f};

    const unsigned short* Ap = A + ((size_t)(bm*256 + wid*64 + l15))*FLATD + l4*8;
    const unsigned short* Bp = Bt + ((size_t)(bn*64 + l15))*FLATD + l4*8;

    #pragma unroll 4
    for (int ks=0; ks<16; ks++){
        int k0 = ks*32;
        bf16x8 af[4], bf[4];
        #pragma unroll
        for (int mf=0;mf<4;mf++) af[mf] = *(const bf16x8*)(Ap + (size_t)mf*16*FLATD + k0);
        #pragma unroll
        for (int nf=0;nf<4;nf++) bf[nf] = *(const bf16x8*)(Bp + (size_t)nf*16*FLATD + k0);
        #pragma unroll
        for (int mf=0;mf<4;mf++)
          #pragma unroll
          for (int nf=0;nf<4;nf++)
            acc[mf][nf] = __builtin_amdgcn_mfma_f32_16x16x32_bf16(af[mf], bf[nf], acc[mf][nf], 0, 0, 0);
    }

    #pragma unroll
    for (int nf=0;nf<4;nf++){
        int col = bn*64 + nf*16 + l15;
        float bias = b1[col];
        #pragma unroll
        for (int mf=0;mf<4;mf++){
            #pragma unroll
            for (int reg=0;reg<4;reg++){
                int row = bm*256 + wid*64 + mf*16 + l4*4 + reg;
                H[(size_t)row*HD + col] = f2bf(fmaxf(acc[mf][nf][reg] + bias, 0.f));
            }
        }
    }
}

// ---------------- Kernel 3: heads via bf16 MFMA. grid (28 m-tiles, 8 heads), 256 threads.
__global__ __launch_bounds__(256) void k_heads_mfma(
    const unsigned short* __restrict__ H, const unsigned short* __restrict__ B2,
    const float* __restrict__ bias2, float* __restrict__ out)
{
    __shared__ short Bs[48][136];
    __shared__ float bsh[48];
    int h = blockIdx.y;
    int m0 = blockIdx.x * 256;
    int t = threadIdx.x;
    int wid = t >> 6, lane = t & 63;
    int l15 = lane & 15, l4 = lane >> 4;

    if (blockIdx.x == 0 && h == 0 && t == 0) out[OFF_TOTAL] = 0.f;

    const unsigned short* Bh = B2 + (size_t)h*48*128;
    for (int i=t; i<768; i+=256){
        int n = i >> 4, kc = (i & 15) * 8;
        *(bf16x8*)&Bs[n][kc] = *(const bf16x8*)(Bh + n*128 + kc);
    }
    if (t < 48) bsh[t] = bias2[h*48 + t];

    f32x4 acc[4][3];
    #pragma unroll
    for (int i=0;i<4;i++)
      #pragma unroll
      for (int j=0;j<3;j++) acc[i][j] = (f32x4){0.f,0.f,0.f,0.f};
    __syncthreads();

    const unsigned short* Ap = H + ((size_t)(m0 + wid*64 + l15))*HD + h*128 + l4*8;
    #pragma unroll
    for (int ks=0; ks<4; ks++){
        int k0 = ks*32;
        bf16x8 af[4], bfr[3];
        #pragma unroll
        for (int mf=0;mf<4;mf++) af[mf] = *(const bf16x8*)(Ap + (size_t)mf*16*HD + k0);
        #pragma unroll
        for (int nf=0;nf<3;nf++) bfr[nf] = *(const bf16x8*)&Bs[nf*16 + l15][l4*8 + k0];
        #pragma unroll
        for (int mf=0;mf<4;mf++)
          #pragma unroll
          for (int nf=0;nf<3;nf++)
            acc[mf][nf] = __builtin_amdgcn_mfma_f32_16x16x32_bf16(af[mf], bfr[nf], acc[mf][nf], 0, 0, 0);
    }

    int Nh = (h==0) ? 38 : ((h==1) ? 25 : 35);
    #pragma unroll
    for (int nf=0;nf<3;nf++){
        int col = nf*16 + l15;
        if (col < Nh){
            float bias = bsh[col];
            #pragma unroll
            for (int mf=0;mf<4;mf++){
                #pragma unroll
                for (int reg=0;reg<4;reg++){
                    int m = m0 + wid*64 + mf*16 + l4*4 + reg;
                    float v = acc[mf][nf][reg] + bias;
                    size_t a;
                    if (h == 0)      a = (size_t)m*38 + col;
                    else if (h == 1) a = OFF_A + (size_t)m*25 + col;
                    else             a = OFF_AD + ((size_t)(h-2)*M_TOT + m)*35 + col;
                    out[a] = v;
                }
            }
        }
    }
}

// ---------------- Kernel 4: per-row group LSEs + losses + mask + total
__global__ __launch_bounds__(256) void k_lse_loss(
    const int* __restrict__ det_t, const int* __restrict__ cls_t,
    float* __restrict__ out)
{
    __shared__ float ls[32][8];
    __shared__ float dls[32];
    int m0 = blockIdx.x * 32;
    int t = threadIdx.x;
    int rr = t >> 3, g = t & 7;
    int m = m0 + rr;
    int r = m / 7;

    const float* p; int n;
    if (g == 0){ p = out + (size_t)m*38; n = 38; }
    else if (g == 1){ p = out + OFF_A + (size_t)m*25; n = 25; }
    else { p = out + OFF_AD + ((size_t)(g-2)*M_TOT + m)*35; n = 35; }

    float mx = -1e30f;
    for (int i=0;i<n;i++) mx = fmaxf(mx, p[i]);
    float s = 0.f;
    for (int i=0;i<n;i++) s += expf(p[i] - mx);
    float lse = mx + logf(s);

    ls[rr][g] = lse - p[cls_t[r*8 + g]];
    if (g == 0) dls[rr] = lse - p[det_t[r]];
    __syncthreads();

    if (g == 0){
        bool mk = dls[rr] < 0.25f;
        out[OFF_MASK + m] = mk ? 1.f : 0.f;
        if (mk){
            float c = 0.f;
            #pragma unroll
            for (int j=0;j<8;j++) c += ls[rr][j];
            atomicAdd(out + OFF_TOTAL, c);
        }
    }
}

extern "C" void kernel_launch(void* const* d_in, const int* in_sizes, int n_in,
                              void* d_out, int out_size, void* d_ws, size_t ws_size,
                              hipStream_t stream) {
    const float* x      = (const float*)d_in[0];
    const int*   rois   = (const int*)d_in[1];
    const int*   det    = (const int*)d_in[2];
    const int*   cls    = (const int*)d_in[3];
    const float* conv_w = (const float*)d_in[4];
    const float* conv_b = (const float*)d_in[5];
    const float* w1     = (const float*)d_in[6];
    const float* b1     = (const float*)d_in[7];
    const float* w2p    = (const float*)d_in[8];
    const float* b2p    = (const float*)d_in[9];
    const float* w2a    = (const float*)d_in[10];
    const float* b2a    = (const float*)d_in[11];
    const float* w2ad   = (const float*)d_in[12];
    const float* b2ad   = (const float*)d_in[13];
    float* out = (float*)d_out;

    char* w = (char*)d_ws;
    unsigned short* flatbf = (unsigned short*)w;                    // 7,340,032 B
    unsigned short* BtW    = (unsigned short*)(w + 7340032);        // 1,048,576 B
    unsigned short* Hbf    = (unsigned short*)(w + 8388608);        // 14,680,064 B
    unsigned short* B2     = (unsigned short*)(w + 23068672);       //    98,304 B
    float*  bias2          = (float*)(w + 23166976);                //     1,536 B
    float*  P              = (float*)(w + 23168512);                // 12,570,624 B

    k_precompute<<<3*1023, 256, 0, stream>>>(x, P);
    k_cvt<<<2240, 256, 0, stream>>>(w1, w2p, b2p, w2a, b2a, w2ad, b2ad, BtW, B2, bias2);
    k_extract<<<M_TOT, 256, 0, stream>>>(P, rois, conv_w, conv_b, flatbf);
    k_fc1_mfma<<<dim3(28, 16), 256, 0, stream>>>(flatbf, BtW, b1, Hbf);
    k_heads_mfma<<<dim3(28, 8), 256, 0, stream>>>(Hbf, B2, bias2, out);
    k_lse_loss<<<224, 256, 0, stream>>>(det, cls, out);
}

// Round 7
// 190.660 us; speedup vs baseline: 1.0268x; 1.0268x over previous
//
#include <hip/hip_runtime.h>

#define NROIS 1024
#define BANDS 7
#define M_TOT (NROIS*BANDS)        // 7168
#define ROI_W 224
#define BAND_H 16
#define FLATD 512
#define HD 1024                     // 8 heads * 128
#define PROV 38
#define ALPHA 25
#define ADC 35
#define NAD 6

#define OFF_A     (M_TOT*PROV)               // 272384
#define OFF_AD    (OFF_A + M_TOT*ALPHA)      // 451584
#define OFF_MASK  (OFF_AD + NAD*M_TOT*ADC)   // 1956864
#define OFF_TOTAL (OFF_MASK + M_TOT)         // 1964032

typedef __attribute__((ext_vector_type(4))) float f32x4;
typedef __attribute__((ext_vector_type(8))) short bf16x8;

static __device__ __forceinline__ unsigned short f2bf(float f){
    union { float f; unsigned int u; } v; v.f = f;
    unsigned int u = v.u;
    unsigned int r = (u + 0x7fffu + ((u >> 16) & 1u)) >> 16;
    return (unsigned short)r;
}

// P2[c][row][s][q] = max over x[c][row..row+1][(14q+s)..(14q+s+13)]
// row in [0,1023), s in [0,14), q in [0,73). Row block = 14*73 = 1022 floats.
#define P2ROW(c,row) (((size_t)((c)*1023 + (row)))*1022)

// ---------------- Kernel 0: precompute sliding 2x14 max into split-residue layout
__global__ __launch_bounds__(256) void k_precompute(
    const float* __restrict__ x, float* __restrict__ P)
{
    __shared__ float v[1024];
    int blk = blockIdx.x;
    int c = blk / 1023, r = blk - c*1023;
    int t = threadIdx.x;
    const float* row0 = x + ((size_t)c*1024 + r)*1024;
    const float* row1 = row0 + 1024;
    #pragma unroll
    for (int i=0;i<4;i++){
        int j = t + i*256;
        v[j] = fmaxf(row0[j], row1[j]);
    }
    __syncthreads();
    float* Pr = P + P2ROW(c, r);
    #pragma unroll
    for (int i=0;i<4;i++){
        int o = t + i*256;               // o = s*73 + q
        if (o < 1022){
            int s = o / 73, q = o - s*73;
            int j = 14*q + s;
            if (j < 1011){
                float mv = v[j];
                #pragma unroll
                for (int d=1;d<14;d++) mv = fmaxf(mv, v[j+d]);
                Pr[o] = mv;              // coalesced write
            }
        }
    }
}

// ---------------- Kernel 1: coalesced gather from P2 -> conv (reg-weights) -> relu -> 2x2 maxpool -> flat bf16
__global__ __launch_bounds__(256) void k_extract(
    const float* __restrict__ P, const int* __restrict__ rois,
    const float* __restrict__ conv_w, const float* __restrict__ conv_b,
    unsigned short* __restrict__ flat)
{
    __shared__ float pl[3][10][19];
    __shared__ float cw[432];
    __shared__ float cb[16];

    int blk = blockIdx.x;
    int r = blk / BANDS, b = blk - r*BANDS;
    int xx = rois[r*4+0];
    int yy = rois[r*4+1] + b*BAND_H;
    int t = threadIdx.x;
    int sx = xx % 14, qx = xx / 14;

    for (int i=t;i<432;i+=256) cw[i]=conv_w[i];
    if (t<16) cb[t]=conv_b[t];
    for (int i=t;i<3*10*19;i+=256) ((float*)pl)[i]=0.f;
    __syncthreads();

    for (int idx=t; idx<384; idx+=256){
        int c = idx>>7; int rem = idx&127; int ph = rem>>4; int pw = rem&15;
        // 16 consecutive floats per (c,ph): fully coalesced 64B segment
        pl[c][ph+1][pw+1] = P[P2ROW(c, yy + 2*ph) + (size_t)sx*73 + qx + pw];
    }
    __syncthreads();

    #pragma unroll
    for (int pass=0; pass<2; pass++){
        int f = t + pass*256;
        int o = f>>5, p=(f>>3)&3, q=f&7;
        float bias = cb[o];
        float s00=bias, s01=bias, s10=bias, s11=bias;
        #pragma unroll
        for (int c=0;c<3;c++){
            float w[9];
            #pragma unroll
            for (int k=0;k<9;k++) w[k] = cw[(o*3+c)*9 + k];
            float pt[4][4];
            #pragma unroll
            for (int di=0; di<4; di++)
              #pragma unroll
              for (int dj=0; dj<4; dj++)
                pt[di][dj] = pl[c][2*p+di][2*q+dj];
            #pragma unroll
            for (int kh=0;kh<3;kh++)
              #pragma unroll
              for (int kw=0;kw<3;kw++){
                float ww = w[kh*3+kw];
                s00 += pt[kh  ][kw  ]*ww;
                s01 += pt[kh  ][kw+1]*ww;
                s10 += pt[kh+1][kw  ]*ww;
                s11 += pt[kh+1][kw+1]*ww;
              }
        }
        float mx = fmaxf(fmaxf(fmaxf(s00,s01), fmaxf(s10,s11)), 0.f);
        flat[(size_t)blk*512 + f] = f2bf(mx);
    }
}

// ---------------- Kernel 1b: all weight conversions in one launch
__global__ __launch_bounds__(256) void k_cvt(
    const float* __restrict__ w1,
    const float* __restrict__ w2p, const float* __restrict__ b2p,
    const float* __restrict__ w2a, const float* __restrict__ b2a,
    const float* __restrict__ w2ad, const float* __restrict__ b2ad,
    unsigned short* __restrict__ Bt, unsigned short* __restrict__ B2,
    float* __restrict__ bias2)
{
    int i = blockIdx.x*256 + threadIdx.x;
    if (i < 524288){
        int k = i >> 10, n = i & 1023;
        float v = w1[((size_t)(n>>7)*512 + k)*128 + (n&127)];
        Bt[(size_t)n*512 + k] = f2bf(v);
    } else {
        int j = i - 524288;          // < 49152
        int h = j / 6144;
        int rem = j - h*6144;
        int n = rem >> 7, k = rem & 127;
        float v = 0.f;
        if (h == 0){ if (n < 38) v = w2p[k*38 + n]; }
        else if (h == 1){ if (n < 25) v = w2a[k*25 + n]; }
        else { if (n < 35) v = w2ad[(size_t)(h-2)*128*35 + k*35 + n]; }
        B2[j] = f2bf(v);
        if (j < 8*48){
            int hh = j / 48, nn = j - hh*48;
            float bv = 0.f;
            if (hh == 0){ if (nn < 38) bv = b2p[nn]; }
            else if (hh == 1){ if (nn < 25) bv = b2a[nn]; }
            else { if (nn < 35) bv = b2ad[(hh-2)*35 + nn]; }
            bias2[j] = bv;
        }
    }
}

// ---------------- Kernel 2: H = relu(flat @ W1cat + b1cat), LDS-free direct-global MFMA
__global__ __launch_bounds__(256) void k_fc1_mfma(
    const unsigned short* __restrict__ A, const unsigned short* __restrict__ Bt,
    const float* __restrict__ b1, unsigned short* __restrict__ H)
{
    int bm = blockIdx.x, bn = blockIdx.y;
    int t = threadIdx.x;
    int wid = t >> 6, lane = t & 63;
    int l15 = lane & 15, l4 = lane >> 4;

    f32x4 acc[4][4];
    #pragma unroll
    for (int i=0;i<4;i++)
      #pragma unroll
      for (int j=0;j<4;j++) acc[i][j] = (f32x4){0.f,0.f,0.f,0.f};

    const unsigned short* Ap = A + ((size_t)(bm*256 + wid*64 + l15))*FLATD + l4*8;
    const unsigned short* Bp = Bt + ((size_t)(bn*64 + l15))*FLATD + l4*8;

    #pragma unroll 4
    for (int ks=0; ks<16; ks++){
        int k0 = ks*32;
        bf16x8 af[4], bf[4];
        #pragma unroll
        for (int mf=0;mf<4;mf++) af[mf] = *(const bf16x8*)(Ap + (size_t)mf*16*FLATD + k0);
        #pragma unroll
        for (int nf=0;nf<4;nf++) bf[nf] = *(const bf16x8*)(Bp + (size_t)nf*16*FLATD + k0);
        #pragma unroll
        for (int mf=0;mf<4;mf++)
          #pragma unroll
          for (int nf=0;nf<4;nf++)
            acc[mf][nf] = __builtin_amdgcn_mfma_f32_16x16x32_bf16(af[mf], bf[nf], acc[mf][nf], 0, 0, 0);
    }

    #pragma unroll
    for (int nf=0;nf<4;nf++){
        int col = bn*64 + nf*16 + l15;
        float bias = b1[col];
        #pragma unroll
        for (int mf=0;mf<4;mf++){
            #pragma unroll
            for (int reg=0;reg<4;reg++){
                int row = bm*256 + wid*64 + mf*16 + l4*4 + reg;
                H[(size_t)row*HD + col] = f2bf(fmaxf(acc[mf][nf][reg] + bias, 0.f));
            }
        }
    }
}

// ---------------- Kernel 3: heads via bf16 MFMA. grid (28 m-tiles, 8 heads), 256 threads.
__global__ __launch_bounds__(256) void k_heads_mfma(
    const unsigned short* __restrict__ H, const unsigned short* __restrict__ B2,
    const float* __restrict__ bias2, float* __restrict__ out)
{
    __shared__ short Bs[48][136];
    __shared__ float bsh[48];
    int h = blockIdx.y;
    int m0 = blockIdx.x * 256;
    int t = threadIdx.x;
    int wid = t >> 6, lane = t & 63;
    int l15 = lane & 15, l4 = lane >> 4;

    if (blockIdx.x == 0 && h == 0 && t == 0) out[OFF_TOTAL] = 0.f;

    const unsigned short* Bh = B2 + (size_t)h*48*128;
    for (int i=t; i<768; i+=256){
        int n = i >> 4, kc = (i & 15) * 8;
        *(bf16x8*)&Bs[n][kc] = *(const bf16x8*)(Bh + n*128 + kc);
    }
    if (t < 48) bsh[t] = bias2[h*48 + t];

    f32x4 acc[4][3];
    #pragma unroll
    for (int i=0;i<4;i++)
      #pragma unroll
      for (int j=0;j<3;j++) acc[i][j] = (f32x4){0.f,0.f,0.f,0.f};
    __syncthreads();

    const unsigned short* Ap = H + ((size_t)(m0 + wid*64 + l15))*HD + h*128 + l4*8;
    #pragma unroll
    for (int ks=0; ks<4; ks++){
        int k0 = ks*32;
        bf16x8 af[4], bfr[3];
        #pragma unroll
        for (int mf=0;mf<4;mf++) af[mf] = *(const bf16x8*)(Ap + (size_t)mf*16*HD + k0);
        #pragma unroll
        for (int nf=0;nf<3;nf++) bfr[nf] = *(const bf16x8*)&Bs[nf*16 + l15][l4*8 + k0];
        #pragma unroll
        for (int mf=0;mf<4;mf++)
          #pragma unroll
          for (int nf=0;nf<3;nf++)
            acc[mf][nf] = __builtin_amdgcn_mfma_f32_16x16x32_bf16(af[mf], bfr[nf], acc[mf][nf], 0, 0, 0);
    }

    int Nh = (h==0) ? 38 : ((h==1) ? 25 : 35);
    #pragma unroll
    for (int nf=0;nf<3;nf++){
        int col = nf*16 + l15;
        if (col < Nh){
            float bias = bsh[col];
            #pragma unroll
            for (int mf=0;mf<4;mf++){
                #pragma unroll
                for (int reg=0;reg<4;reg++){
                    int m = m0 + wid*64 + mf*16 + l4*4 + reg;
                    float v = acc[mf][nf][reg] + bias;
                    size_t a;
                    if (h == 0)      a = (size_t)m*38 + col;
                    else if (h == 1) a = OFF_A + (size_t)m*25 + col;
                    else             a = OFF_AD + ((size_t)(h-2)*M_TOT + m)*35 + col;
                    out[a] = v;
                }
            }
        }
    }
}

// ---------------- Kernel 4: per-row group LSEs + losses + mask + total
__global__ __launch_bounds__(256) void k_lse_loss(
    const int* __restrict__ det_t, const int* __restrict__ cls_t,
    float* __restrict__ out)
{
    __shared__ float ls[32][8];
    __shared__ float dls[32];
    int m0 = blockIdx.x * 32;
    int t = threadIdx.x;
    int rr = t >> 3, g = t & 7;
    int m = m0 + rr;
    int r = m / 7;

    const float* p; int n;
    if (g == 0){ p = out + (size_t)m*38; n = 38; }
    else if (g == 1){ p = out + OFF_A + (size_t)m*25; n = 25; }
    else { p = out + OFF_AD + ((size_t)(g-2)*M_TOT + m)*35; n = 35; }

    float mx = -1e30f;
    for (int i=0;i<n;i++) mx = fmaxf(mx, p[i]);
    float s = 0.f;
    for (int i=0;i<n;i++) s += expf(p[i] - mx);
    float lse = mx + logf(s);

    ls[rr][g] = lse - p[cls_t[r*8 + g]];
    if (g == 0) dls[rr] = lse - p[det_t[r]];
    __syncthreads();

    if (g == 0){
        bool mk = dls[rr] < 0.25f;
        out[OFF_MASK + m] = mk ? 1.f : 0.f;
        if (mk){
            float c = 0.f;
            #pragma unroll
            for (int j=0;j<8;j++) c += ls[rr][j];
            atomicAdd(out + OFF_TOTAL, c);
        }
    }
}

extern "C" void kernel_launch(void* const* d_in, const int* in_sizes, int n_in,
                              void* d_out, int out_size, void* d_ws, size_t ws_size,
                              hipStream_t stream) {
    const float* x      = (const float*)d_in[0];
    const int*   rois   = (const int*)d_in[1];
    const int*   det    = (const int*)d_in[2];
    const int*   cls    = (const int*)d_in[3];
    const float* conv_w = (const float*)d_in[4];
    const float* conv_b = (const float*)d_in[5];
    const float* w1     = (const float*)d_in[6];
    const float* b1     = (const float*)d_in[7];
    const float* w2p    = (const float*)d_in[8];
    const float* b2p    = (const float*)d_in[9];
    const float* w2a    = (const float*)d_in[10];
    const float* b2a    = (const float*)d_in[11];
    const float* w2ad   = (const float*)d_in[12];
    const float* b2ad   = (const float*)d_in[13];
    float* out = (float*)d_out;

    char* w = (char*)d_ws;
    unsigned short* flatbf = (unsigned short*)w;                    // 7,340,032 B
    unsigned short* BtW    = (unsigned short*)(w + 7340032);        // 1,048,576 B
    unsigned short* Hbf    = (unsigned short*)(w + 8388608);        // 14,680,064 B
    unsigned short* B2     = (unsigned short*)(w + 23068672);       //    98,304 B
    float*  bias2          = (float*)(w + 23166976);                //     1,536 B
    float*  P              = (float*)(w + 23168512);                // 12,546,072 B

    k_precompute<<<3*1023, 256, 0, stream>>>(x, P);
    k_cvt<<<2240, 256, 0, stream>>>(w1, w2p, b2p, w2a, b2a, w2ad, b2ad, BtW, B2, bias2);
    k_extract<<<M_TOT, 256, 0, stream>>>(P, rois, conv_w, conv_b, flatbf);
    k_fc1_mfma<<<dim3(28, 16), 256, 0, stream>>>(flatbf, BtW, b1, Hbf);
    k_heads_mfma<<<dim3(28, 8), 256, 0, stream>>>(Hbf, B2, bias2, out);
    k_lse_loss<<<224, 256, 0, stream>>>(det, cls, out);
}

// Round 8
// 170.971 us; speedup vs baseline: 1.1451x; 1.1152x over previous
//
#include <hip/hip_runtime.h>

#define NROIS 1024
#define BANDS 7
#define M_TOT (NROIS*BANDS)        // 7168
#define ROI_W 224
#define BAND_H 16
#define FLATD 512
#define HD 1024                     // 8 heads * 128
#define PROV 38
#define ALPHA 25
#define ADC 35
#define NAD 6

#define OFF_A     (M_TOT*PROV)               // 272384
#define OFF_AD    (OFF_A + M_TOT*ALPHA)      // 451584
#define OFF_MASK  (OFF_AD + NAD*M_TOT*ADC)   // 1956864
#define OFF_TOTAL (OFF_MASK + M_TOT)         // 1964032

typedef __attribute__((ext_vector_type(4))) float f32x4;
typedef __attribute__((ext_vector_type(8))) short bf16x8;

static __device__ __forceinline__ unsigned short f2bf(float f){
    union { float f; unsigned int u; } v; v.f = f;
    unsigned int u = v.u;
    unsigned int r = (u + 0x7fffu + ((u >> 16) & 1u)) >> 16;
    return (unsigned short)r;
}

// async global->LDS, 16B per lane, wave-uniform LDS base + lane*16
#define GL16(gp, lp) __builtin_amdgcn_global_load_lds( \
    (const __attribute__((address_space(1))) unsigned int*)(gp), \
    (__attribute__((address_space(3))) unsigned int*)(lp), 16, 0, 0)

// P2[c][row][s][q] = max over x[c][row..row+1][(14q+s)..(14q+s+13)]
#define P2ROW(c,row) (((size_t)((c)*1023 + (row)))*1022)

// ---------------- Kernel 0: fused precompute P2 + weight conversions
__global__ __launch_bounds__(256) void k_pre_cvt(
    const float* __restrict__ x, const float* __restrict__ w1,
    const float* __restrict__ w2p, const float* __restrict__ b2p,
    const float* __restrict__ w2a, const float* __restrict__ b2a,
    const float* __restrict__ w2ad, const float* __restrict__ b2ad,
    float* __restrict__ P, unsigned short* __restrict__ Bt,
    unsigned short* __restrict__ B2, float* __restrict__ bias2)
{
    __shared__ float v[1024];
    int blk = blockIdx.x;
    int t = threadIdx.x;
    if (blk < 3069){
        int c = blk / 1023, r = blk - c*1023;
        const float* row0 = x + ((size_t)c*1024 + r)*1024;
        const float* row1 = row0 + 1024;
        #pragma unroll
        for (int i=0;i<4;i++){
            int j = t + i*256;
            v[j] = fmaxf(row0[j], row1[j]);
        }
        __syncthreads();
        float* Pr = P + P2ROW(c, r);
        #pragma unroll
        for (int i=0;i<4;i++){
            int o = t + i*256;               // o = s*73 + q
            if (o < 1022){
                int s = o / 73, q = o - s*73;
                int j = 14*q + s;
                if (j < 1011){
                    float mv = v[j];
                    #pragma unroll
                    for (int d=1;d<14;d++) mv = fmaxf(mv, v[j+d]);
                    Pr[o] = mv;
                }
            }
        }
    } else {
        int i = (blk - 3069)*256 + t;
        if (i < 524288){
            int k = i >> 10, n = i & 1023;
            float val = w1[((size_t)(n>>7)*512 + k)*128 + (n&127)];
            Bt[(size_t)n*512 + k] = f2bf(val);
        } else {
            int j = i - 524288;          // < 49152
            int h = j / 6144;
            int rem = j - h*6144;
            int n = rem >> 7, k = rem & 127;
            float val = 0.f;
            if (h == 0){ if (n < 38) val = w2p[k*38 + n]; }
            else if (h == 1){ if (n < 25) val = w2a[k*25 + n]; }
            else { if (n < 35) val = w2ad[(size_t)(h-2)*128*35 + k*35 + n]; }
            B2[j] = f2bf(val);
            if (j < 8*48){
                int hh = j / 48, nn = j - hh*48;
                float bv = 0.f;
                if (hh == 0){ if (nn < 38) bv = b2p[nn]; }
                else if (hh == 1){ if (nn < 25) bv = b2a[nn]; }
                else { if (nn < 35) bv = b2ad[(hh-2)*35 + nn]; }
                bias2[j] = bv;
            }
        }
    }
}

// ---------------- Kernel 1: coalesced gather from P2 -> conv -> relu -> 2x2 maxpool -> flat bf16
__global__ __launch_bounds__(256) void k_extract(
    const float* __restrict__ P, const int* __restrict__ rois,
    const float* __restrict__ conv_w, const float* __restrict__ conv_b,
    unsigned short* __restrict__ flat)
{
    __shared__ float pl[3][10][19];
    __shared__ float cw[432];
    __shared__ float cb[16];

    int blk = blockIdx.x;
    int r = blk / BANDS, b = blk - r*BANDS;
    int xx = rois[r*4+0];
    int yy = rois[r*4+1] + b*BAND_H;
    int t = threadIdx.x;
    int sx = xx % 14, qx = xx / 14;

    for (int i=t;i<432;i+=256) cw[i]=conv_w[i];
    if (t<16) cb[t]=conv_b[t];
    for (int i=t;i<3*10*19;i+=256) ((float*)pl)[i]=0.f;
    __syncthreads();

    for (int idx=t; idx<384; idx+=256){
        int c = idx>>7; int rem = idx&127; int ph = rem>>4; int pw = rem&15;
        pl[c][ph+1][pw+1] = P[P2ROW(c, yy + 2*ph) + (size_t)sx*73 + qx + pw];
    }
    __syncthreads();

    #pragma unroll
    for (int pass=0; pass<2; pass++){
        int f = t + pass*256;
        int o = f>>5, p=(f>>3)&3, q=f&7;
        float bias = cb[o];
        float s00=bias, s01=bias, s10=bias, s11=bias;
        #pragma unroll
        for (int c=0;c<3;c++){
            float w[9];
            #pragma unroll
            for (int k=0;k<9;k++) w[k] = cw[(o*3+c)*9 + k];
            float pt[4][4];
            #pragma unroll
            for (int di=0; di<4; di++)
              #pragma unroll
              for (int dj=0; dj<4; dj++)
                pt[di][dj] = pl[c][2*p+di][2*q+dj];
            #pragma unroll
            for (int kh=0;kh<3;kh++)
              #pragma unroll
              for (int kw=0;kw<3;kw++){
                float ww = w[kh*3+kw];
                s00 += pt[kh  ][kw  ]*ww;
                s01 += pt[kh  ][kw+1]*ww;
                s10 += pt[kh+1][kw  ]*ww;
                s11 += pt[kh+1][kw+1]*ww;
              }
        }
        float mx = fmaxf(fmaxf(fmaxf(s00,s01), fmaxf(s10,s11)), 0.f);
        flat[(size_t)blk*512 + f] = f2bf(mx);
    }
}

// ---------------- Kernel 2: H = relu(flat @ W1cat + b1cat)
// 128x64 tile, 4 waves (2x2), global_load_lds staging, 2-phase double buffer.
__global__ __launch_bounds__(256) void k_fc1_v3(
    const unsigned short* __restrict__ A, const unsigned short* __restrict__ Bt,
    const float* __restrict__ b1, unsigned short* __restrict__ H)
{
    __shared__ short As[2][4096];   // [buf][128 rows x 32 k] linear
    __shared__ short Bs[2][2048];   // [buf][64 rows x 32 k]  linear
    int bm = blockIdx.x, bn = blockIdx.y;
    int t = threadIdx.x;
    int wid = t >> 6, lane = t & 63;
    int wr = wid >> 1, wc = wid & 1;
    int l15 = lane & 15, l4 = lane >> 4;

    // staging source: wave wid covers 16 rows per issue; lane l -> row wid*16 + l/4, kc (l&3)*8
    const unsigned short* gA = A + ((size_t)(bm*128 + wid*16 + (lane>>2)))*FLATD + (lane&3)*8;
    const unsigned short* gB = Bt + ((size_t)(bn*64  + wid*16 + (lane>>2)))*FLATD + (lane&3)*8;

    f32x4 acc[4][2];
    #pragma unroll
    for (int i=0;i<4;i++){ acc[i][0]=(f32x4){0,0,0,0}; acc[i][1]=(f32x4){0,0,0,0}; }

    // prologue: stage k=0 into buf 0
    GL16(gA,            &As[0][wid*512]);
    GL16(gA + 64*FLATD, &As[0][2048 + wid*512]);
    GL16(gB,            &Bs[0][wid*512]);
    __syncthreads();

    #pragma unroll
    for (int ks=0; ks<16; ks++){
        int cur = ks & 1;
        if (ks < 15){
            int k1 = (ks+1)*32;
            GL16(gA + k1,            &As[cur^1][wid*512]);
            GL16(gA + 64*FLATD + k1, &As[cur^1][2048 + wid*512]);
            GL16(gB + k1,            &Bs[cur^1][wid*512]);
        }
        bf16x8 af[4], bfv[2];
        #pragma unroll
        for (int mf=0;mf<4;mf++) af[mf]  = *(const bf16x8*)&As[cur][(wr*64 + mf*16 + l15)*32 + l4*8];
        #pragma unroll
        for (int nf=0;nf<2;nf++) bfv[nf] = *(const bf16x8*)&Bs[cur][(wc*32 + nf*16 + l15)*32 + l4*8];
        #pragma unroll
        for (int mf=0;mf<4;mf++)
          #pragma unroll
          for (int nf=0;nf<2;nf++)
            acc[mf][nf] = __builtin_amdgcn_mfma_f32_16x16x32_bf16(af[mf], bfv[nf], acc[mf][nf], 0, 0, 0);
        __syncthreads();   // drains staging loads (vmcnt0) + guards buffer reuse
    }

    #pragma unroll
    for (int nf=0;nf<2;nf++){
        int col = bn*64 + wc*32 + nf*16 + l15;
        float bias = b1[col];
        #pragma unroll
        for (int mf=0;mf<4;mf++){
            #pragma unroll
            for (int reg=0;reg<4;reg++){
                int row = bm*128 + wr*64 + mf*16 + l4*4 + reg;
                H[(size_t)row*HD + col] = f2bf(fmaxf(acc[mf][nf][reg] + bias, 0.f));
            }
        }
    }
}

// ---------------- Kernel 3: heads via bf16 MFMA. grid (28 m-tiles, 8 heads), 256 threads.
__global__ __launch_bounds__(256) void k_heads_mfma(
    const unsigned short* __restrict__ H, const unsigned short* __restrict__ B2,
    const float* __restrict__ bias2, float* __restrict__ out)
{
    __shared__ short Bs[48][136];
    __shared__ float bsh[48];
    int h = blockIdx.y;
    int m0 = blockIdx.x * 256;
    int t = threadIdx.x;
    int wid = t >> 6, lane = t & 63;
    int l15 = lane & 15, l4 = lane >> 4;

    if (blockIdx.x == 0 && h == 0 && t == 0) out[OFF_TOTAL] = 0.f;

    const unsigned short* Bh = B2 + (size_t)h*48*128;
    for (int i=t; i<768; i+=256){
        int n = i >> 4, kc = (i & 15) * 8;
        *(bf16x8*)&Bs[n][kc] = *(const bf16x8*)(Bh + n*128 + kc);
    }
    if (t < 48) bsh[t] = bias2[h*48 + t];

    f32x4 acc[4][3];
    #pragma unroll
    for (int i=0;i<4;i++)
      #pragma unroll
      for (int j=0;j<3;j++) acc[i][j] = (f32x4){0.f,0.f,0.f,0.f};
    __syncthreads();

    const unsigned short* Ap = H + ((size_t)(m0 + wid*64 + l15))*HD + h*128 + l4*8;
    #pragma unroll
    for (int ks=0; ks<4; ks++){
        int k0 = ks*32;
        bf16x8 af[4], bfr[3];
        #pragma unroll
        for (int mf=0;mf<4;mf++) af[mf] = *(const bf16x8*)(Ap + (size_t)mf*16*HD + k0);
        #pragma unroll
        for (int nf=0;nf<3;nf++) bfr[nf] = *(const bf16x8*)&Bs[nf*16 + l15][l4*8 + k0];
        #pragma unroll
        for (int mf=0;mf<4;mf++)
          #pragma unroll
          for (int nf=0;nf<3;nf++)
            acc[mf][nf] = __builtin_amdgcn_mfma_f32_16x16x32_bf16(af[mf], bfr[nf], acc[mf][nf], 0, 0, 0);
    }

    int Nh = (h==0) ? 38 : ((h==1) ? 25 : 35);
    #pragma unroll
    for (int nf=0;nf<3;nf++){
        int col = nf*16 + l15;
        if (col < Nh){
            float bias = bsh[col];
            #pragma unroll
            for (int mf=0;mf<4;mf++){
                #pragma unroll
                for (int reg=0;reg<4;reg++){
                    int m = m0 + wid*64 + mf*16 + l4*4 + reg;
                    float v = acc[mf][nf][reg] + bias;
                    size_t a;
                    if (h == 0)      a = (size_t)m*38 + col;
                    else if (h == 1) a = OFF_A + (size_t)m*25 + col;
                    else             a = OFF_AD + ((size_t)(h-2)*M_TOT + m)*35 + col;
                    out[a] = v;
                }
            }
        }
    }
}

// ---------------- Kernel 4: per-row group LSEs + losses + mask + total
__global__ __launch_bounds__(256) void k_lse_loss(
    const int* __restrict__ det_t, const int* __restrict__ cls_t,
    float* __restrict__ out)
{
    __shared__ float ls[32][8];
    __shared__ float dls[32];
    int m0 = blockIdx.x * 32;
    int t = threadIdx.x;
    int rr = t >> 3, g = t & 7;
    int m = m0 + rr;
    int r = m / 7;

    const float* p; int n;
    if (g == 0){ p = out + (size_t)m*38; n = 38; }
    else if (g == 1){ p = out + OFF_A + (size_t)m*25; n = 25; }
    else { p = out + OFF_AD + ((size_t)(g-2)*M_TOT + m)*35; n = 35; }

    float mx = -1e30f;
    for (int i=0;i<n;i++) mx = fmaxf(mx, p[i]);
    float s = 0.f;
    for (int i=0;i<n;i++) s += expf(p[i] - mx);
    float lse = mx + logf(s);

    ls[rr][g] = lse - p[cls_t[r*8 + g]];
    if (g == 0) dls[rr] = lse - p[det_t[r]];
    __syncthreads();

    if (g == 0){
        bool mk = dls[rr] < 0.25f;
        out[OFF_MASK + m] = mk ? 1.f : 0.f;
        if (mk){
            float c = 0.f;
            #pragma unroll
            for (int j=0;j<8;j++) c += ls[rr][j];
            atomicAdd(out + OFF_TOTAL, c);
        }
    }
}

extern "C" void kernel_launch(void* const* d_in, const int* in_sizes, int n_in,
                              void* d_out, int out_size, void* d_ws, size_t ws_size,
                              hipStream_t stream) {
    const float* x      = (const float*)d_in[0];
    const int*   rois   = (const int*)d_in[1];
    const int*   det    = (const int*)d_in[2];
    const int*   cls    = (const int*)d_in[3];
    const float* conv_w = (const float*)d_in[4];
    const float* conv_b = (const float*)d_in[5];
    const float* w1     = (const float*)d_in[6];
    const float* b1     = (const float*)d_in[7];
    const float* w2p    = (const float*)d_in[8];
    const float* b2p    = (const float*)d_in[9];
    const float* w2a    = (const float*)d_in[10];
    const float* b2a    = (const float*)d_in[11];
    const float* w2ad   = (const float*)d_in[12];
    const float* b2ad   = (const float*)d_in[13];
    float* out = (float*)d_out;

    char* w = (char*)d_ws;
    unsigned short* flatbf = (unsigned short*)w;                    // 7,340,032 B
    unsigned short* BtW    = (unsigned short*)(w + 7340032);        // 1,048,576 B
    unsigned short* Hbf    = (unsigned short*)(w + 8388608);        // 14,680,064 B
    unsigned short* B2     = (unsigned short*)(w + 23068672);       //    98,304 B
    float*  bias2          = (float*)(w + 23166976);                //     1,536 B
    float*  P              = (float*)(w + 23168512);                // 12,546,072 B

    k_pre_cvt<<<3069 + 2240, 256, 0, stream>>>(x, w1, w2p, b2p, w2a, b2a, w2ad, b2ad,
                                               P, BtW, B2, bias2);
    k_extract<<<M_TOT, 256, 0, stream>>>(P, rois, conv_w, conv_b, flatbf);
    k_fc1_v3<<<dim3(56, 16), 256, 0, stream>>>(flatbf, BtW, b1, Hbf);
    k_heads_mfma<<<dim3(28, 8), 256, 0, stream>>>(Hbf, B2, bias2, out);
    k_lse_loss<<<224, 256, 0, stream>>>(det, cls, out);
}

// Round 9
// 151.703 us; speedup vs baseline: 1.2905x; 1.1270x over previous
//
#include <hip/hip_runtime.h>

#define NROIS 1024
#define BANDS 7
#define M_TOT (NROIS*BANDS)        // 7168
#define ROI_W 224
#define BAND_H 16
#define FLATD 512
#define HD 1024                     // 8 heads * 128
#define PROV 38
#define ALPHA 25
#define ADC 35
#define NAD 6

#define OFF_A     (M_TOT*PROV)               // 272384
#define OFF_AD    (OFF_A + M_TOT*ALPHA)      // 451584
#define OFF_MASK  (OFF_AD + NAD*M_TOT*ADC)   // 1956864
#define OFF_TOTAL (OFF_MASK + M_TOT)         // 1964032

typedef __attribute__((ext_vector_type(4))) float f32x4;
typedef __attribute__((ext_vector_type(8))) short bf16x8;

static __device__ __forceinline__ unsigned short f2bf(float f){
    union { float f; unsigned int u; } v; v.f = f;
    unsigned int u = v.u;
    unsigned int r = (u + 0x7fffu + ((u >> 16) & 1u)) >> 16;
    return (unsigned short)r;
}

// async global->LDS, 16B per lane, wave-uniform LDS base + lane*16
#define GL16(gp, lp) __builtin_amdgcn_global_load_lds( \
    (const __attribute__((address_space(1))) unsigned int*)(gp), \
    (__attribute__((address_space(3))) unsigned int*)(lp), 16, 0, 0)

// P2[c][row][s][q] = max over x[c][row..row+1][(14q+s)..(14q+s+13)]
#define P2ROW(c,row) (((size_t)((c)*1023 + (row)))*1022)

// ---------------- Kernel 0: fused precompute P2 + weight conversions
__global__ __launch_bounds__(256) void k_pre_cvt(
    const float* __restrict__ x, const float* __restrict__ w1,
    const float* __restrict__ w2p, const float* __restrict__ b2p,
    const float* __restrict__ w2a, const float* __restrict__ b2a,
    const float* __restrict__ w2ad, const float* __restrict__ b2ad,
    float* __restrict__ P, unsigned short* __restrict__ Bt,
    unsigned short* __restrict__ B2, float* __restrict__ bias2)
{
    __shared__ float v[1024];
    int blk = blockIdx.x;
    int t = threadIdx.x;
    if (blk < 3069){
        int c = blk / 1023, r = blk - c*1023;
        const float* row0 = x + ((size_t)c*1024 + r)*1024;
        const float* row1 = row0 + 1024;
        #pragma unroll
        for (int i=0;i<4;i++){
            int j = t + i*256;
            v[j] = fmaxf(row0[j], row1[j]);
        }
        __syncthreads();
        float* Pr = P + P2ROW(c, r);
        #pragma unroll
        for (int i=0;i<4;i++){
            int o = t + i*256;               // o = s*73 + q
            if (o < 1022){
                int s = o / 73, q = o - s*73;
                int j = 14*q + s;
                if (j < 1011){
                    float mv = v[j];
                    #pragma unroll
                    for (int d=1;d<14;d++) mv = fmaxf(mv, v[j+d]);
                    Pr[o] = mv;
                }
            }
        }
    } else {
        int i = (blk - 3069)*256 + t;
        if (i < 524288){
            int k = i >> 10, n = i & 1023;
            float val = w1[((size_t)(n>>7)*512 + k)*128 + (n&127)];
            Bt[(size_t)n*512 + k] = f2bf(val);
        } else {
            int j = i - 524288;          // < 49152
            int h = j / 6144;
            int rem = j - h*6144;
            int n = rem >> 7, k = rem & 127;
            float val = 0.f;
            if (h == 0){ if (n < 38) val = w2p[k*38 + n]; }
            else if (h == 1){ if (n < 25) val = w2a[k*25 + n]; }
            else { if (n < 35) val = w2ad[(size_t)(h-2)*128*35 + k*35 + n]; }
            B2[j] = f2bf(val);
            if (j < 8*48){
                int hh = j / 48, nn = j - hh*48;
                float bv = 0.f;
                if (hh == 0){ if (nn < 38) bv = b2p[nn]; }
                else if (hh == 1){ if (nn < 25) bv = b2a[nn]; }
                else { if (nn < 35) bv = b2ad[(hh-2)*35 + nn]; }
                bias2[j] = bv;
            }
        }
    }
}

// ---------------- Kernel 1: coalesced gather from P2 -> conv -> relu -> 2x2 maxpool -> flat bf16
__global__ __launch_bounds__(256) void k_extract(
    const float* __restrict__ P, const int* __restrict__ rois,
    const float* __restrict__ conv_w, const float* __restrict__ conv_b,
    unsigned short* __restrict__ flat)
{
    __shared__ float pl[3][10][19];
    __shared__ float cw[432];
    __shared__ float cb[16];

    int blk = blockIdx.x;
    int r = blk / BANDS, b = blk - r*BANDS;
    int xx = rois[r*4+0];
    int yy = rois[r*4+1] + b*BAND_H;
    int t = threadIdx.x;
    int sx = xx % 14, qx = xx / 14;

    for (int i=t;i<432;i+=256) cw[i]=conv_w[i];
    if (t<16) cb[t]=conv_b[t];
    for (int i=t;i<3*10*19;i+=256) ((float*)pl)[i]=0.f;
    __syncthreads();

    for (int idx=t; idx<384; idx+=256){
        int c = idx>>7; int rem = idx&127; int ph = rem>>4; int pw = rem&15;
        pl[c][ph+1][pw+1] = P[P2ROW(c, yy + 2*ph) + (size_t)sx*73 + qx + pw];
    }
    __syncthreads();

    #pragma unroll
    for (int pass=0; pass<2; pass++){
        int f = t + pass*256;
        int o = f>>5, p=(f>>3)&3, q=f&7;
        float bias = cb[o];
        float s00=bias, s01=bias, s10=bias, s11=bias;
        #pragma unroll
        for (int c=0;c<3;c++){
            float w[9];
            #pragma unroll
            for (int k=0;k<9;k++) w[k] = cw[(o*3+c)*9 + k];
            float pt[4][4];
            #pragma unroll
            for (int di=0; di<4; di++)
              #pragma unroll
              for (int dj=0; dj<4; dj++)
                pt[di][dj] = pl[c][2*p+di][2*q+dj];
            #pragma unroll
            for (int kh=0;kh<3;kh++)
              #pragma unroll
              for (int kw=0;kw<3;kw++){
                float ww = w[kh*3+kw];
                s00 += pt[kh  ][kw  ]*ww;
                s01 += pt[kh  ][kw+1]*ww;
                s10 += pt[kh+1][kw  ]*ww;
                s11 += pt[kh+1][kw+1]*ww;
              }
        }
        float mx = fmaxf(fmaxf(fmaxf(s00,s01), fmaxf(s10,s11)), 0.f);
        flat[(size_t)blk*512 + f] = f2bf(mx);
    }
}

// ---------------- Kernel 2: fused fc1 + heads + per-row LSE
// grid (56 m-tiles of 128, 8 heads), 256 threads (4 waves).
// Phase 1: H_tile(128x128) = relu(flat_tile @ W1[:,head]) via staged MFMA (2-phase dbuf).
// Phase 2: H_tile -> LDS bf16; logits = H_tile @ W2[head] + bias2; write logits + LSE.
__global__ __launch_bounds__(256) void k_fc1_heads(
    const unsigned short* __restrict__ A, const unsigned short* __restrict__ Bt,
    const float* __restrict__ b1, const unsigned short* __restrict__ B2,
    const float* __restrict__ bias2, float* __restrict__ out,
    float* __restrict__ lse_ws)
{
    __shared__ short smem[16896];              // union: staging (16384) / Hl (16896)
    short* As = smem;                          // As[2][4096]
    short* Bs = smem + 8192;                   // Bs[2][4096]
    short* Hl = smem;                          // Hl[128][132]

    int bm = blockIdx.x, h = blockIdx.y;
    int m0 = bm*128;
    int t = threadIdx.x;
    int wid = t >> 6, lane = t & 63;
    int wr = wid >> 1, wc = wid & 1;
    int l15 = lane & 15, l4 = lane >> 4;

    if (bm == 0 && h == 0 && t == 0) out[OFF_TOTAL] = 0.f;

    const unsigned short* gA = A  + ((size_t)(m0    + wid*16 + (lane>>2)))*FLATD + (lane&3)*8;
    const unsigned short* gB = Bt + ((size_t)(h*128 + wid*16 + (lane>>2)))*FLATD + (lane&3)*8;

    f32x4 acc[4][4];
    #pragma unroll
    for (int i=0;i<4;i++)
      #pragma unroll
      for (int j=0;j<4;j++) acc[i][j] = (f32x4){0.f,0.f,0.f,0.f};

    // prologue: stage k=0 into buf 0
    GL16(gA,            As + wid*512);
    GL16(gA + 64*FLATD, As + 2048 + wid*512);
    GL16(gB,            Bs + wid*512);
    GL16(gB + 64*FLATD, Bs + 2048 + wid*512);
    __syncthreads();

    #pragma unroll
    for (int ks=0; ks<16; ks++){
        int cur = ks & 1;
        if (ks < 15){
            int k1 = (ks+1)*32;
            int nb = (cur^1)*4096;
            GL16(gA + k1,            As + nb + wid*512);
            GL16(gA + 64*FLATD + k1, As + nb + 2048 + wid*512);
            GL16(gB + k1,            Bs + nb + wid*512);
            GL16(gB + 64*FLATD + k1, Bs + nb + 2048 + wid*512);
        }
        bf16x8 af[4], bfv[4];
        #pragma unroll
        for (int mf=0;mf<4;mf++) af[mf]  = *(const bf16x8*)&As[cur*4096 + (wr*64 + mf*16 + l15)*32 + l4*8];
        #pragma unroll
        for (int nf=0;nf<4;nf++) bfv[nf] = *(const bf16x8*)&Bs[cur*4096 + (wc*64 + nf*16 + l15)*32 + l4*8];
        #pragma unroll
        for (int mf=0;mf<4;mf++)
          #pragma unroll
          for (int nf=0;nf<4;nf++)
            acc[mf][nf] = __builtin_amdgcn_mfma_f32_16x16x32_bf16(af[mf], bfv[nf], acc[mf][nf], 0, 0, 0);
        __syncthreads();
    }

    // Phase 2a: H tile -> LDS (bf16, bias+relu applied)
    #pragma unroll
    for (int nf=0;nf<4;nf++){
        int col = wc*64 + nf*16 + l15;
        float bias = b1[h*128 + col];
        #pragma unroll
        for (int mf=0;mf<4;mf++){
            #pragma unroll
            for (int reg=0;reg<4;reg++){
                int row = wr*64 + mf*16 + l4*4 + reg;
                Hl[row*132 + col] = (short)f2bf(fmaxf(acc[mf][nf][reg] + bias, 0.f));
            }
        }
    }
    __syncthreads();

    // Phase 2b: logits = H_tile @ W2[head]; wave wid owns rows wid*32..+31
    f32x4 acc2[2][3];
    #pragma unroll
    for (int i=0;i<2;i++)
      #pragma unroll
      for (int j=0;j<3;j++) acc2[i][j] = (f32x4){0.f,0.f,0.f,0.f};

    const unsigned short* Bh = B2 + (size_t)h*6144;
    #pragma unroll
    for (int ks=0; ks<4; ks++){
        bf16x8 ha[2], hb[3];
        #pragma unroll
        for (int m2=0;m2<2;m2++)
            ha[m2] = *(const bf16x8*)&Hl[(wid*32 + m2*16 + l15)*132 + ks*32 + l4*8];
        #pragma unroll
        for (int nf=0;nf<3;nf++)
            hb[nf] = *(const bf16x8*)(Bh + (nf*16 + l15)*128 + ks*32 + l4*8);
        #pragma unroll
        for (int m2=0;m2<2;m2++)
          #pragma unroll
          for (int nf=0;nf<3;nf++)
            acc2[m2][nf] = __builtin_amdgcn_mfma_f32_16x16x32_bf16(ha[m2], hb[nf], acc2[m2][nf], 0, 0, 0);
    }

    int Nh = (h==0) ? 38 : ((h==1) ? 25 : 35);
    // add bias, write logits
    #pragma unroll
    for (int nf=0;nf<3;nf++){
        int col = nf*16 + l15;
        float bv = bias2[h*48 + col];
        #pragma unroll
        for (int m2=0;m2<2;m2++){
            #pragma unroll
            for (int reg=0;reg<4;reg++){
                acc2[m2][nf][reg] += bv;
                if (col < Nh){
                    int m = m0 + wid*32 + m2*16 + l4*4 + reg;
                    size_t a;
                    if (h == 0)      a = (size_t)m*38 + col;
                    else if (h == 1) a = OFF_A + (size_t)m*25 + col;
                    else             a = OFF_AD + ((size_t)(h-2)*M_TOT + m)*35 + col;
                    out[a] = acc2[m2][nf][reg];
                }
            }
        }
    }

    // Phase 2c: per-row LSE via 16-lane shfl reduce (lanes sharing l4)
    #pragma unroll
    for (int m2=0;m2<2;m2++){
        #pragma unroll
        for (int reg=0;reg<4;reg++){
            float mx = -1e30f;
            #pragma unroll
            for (int nf=0;nf<3;nf++){
                int col = nf*16 + l15;
                if (col < Nh) mx = fmaxf(mx, acc2[m2][nf][reg]);
            }
            #pragma unroll
            for (int d=1; d<16; d<<=1) mx = fmaxf(mx, __shfl_xor(mx, d));
            float s = 0.f;
            #pragma unroll
            for (int nf=0;nf<3;nf++){
                int col = nf*16 + l15;
                if (col < Nh) s += __expf(acc2[m2][nf][reg] - mx);
            }
            #pragma unroll
            for (int d=1; d<16; d<<=1) s += __shfl_xor(s, d);
            if (l15 == 0){
                int m = m0 + wid*32 + m2*16 + l4*4 + reg;
                lse_ws[(size_t)m*8 + h] = mx + __logf(s);
            }
        }
    }
}

// ---------------- Kernel 3: per-row losses + mask + total (reads lse_ws + target logits)
__global__ __launch_bounds__(256) void k_loss(
    const float* __restrict__ lse_ws, const int* __restrict__ det_t,
    const int* __restrict__ cls_t, float* __restrict__ out)
{
    int m = blockIdx.x*256 + threadIdx.x;
    if (m >= M_TOT) return;
    int r = m / 7;
    const float* L = lse_ws + (size_t)m*8;
    float det_loss = L[0] - out[(size_t)m*38 + det_t[r]];
    bool mk = det_loss < 0.25f;
    out[OFF_MASK + m] = mk ? 1.f : 0.f;
    if (mk){
        const int* ct = cls_t + r*8;
        float c = (L[0] - out[(size_t)m*38 + ct[0]]) + (L[1] - out[OFF_A + (size_t)m*25 + ct[1]]);
        #pragma unroll
        for (int j=0;j<6;j++)
            c += L[2+j] - out[OFF_AD + ((size_t)j*M_TOT + m)*35 + ct[2+j]];
        atomicAdd(out + OFF_TOTAL, c);
    }
}

extern "C" void kernel_launch(void* const* d_in, const int* in_sizes, int n_in,
                              void* d_out, int out_size, void* d_ws, size_t ws_size,
                              hipStream_t stream) {
    const float* x      = (const float*)d_in[0];
    const int*   rois   = (const int*)d_in[1];
    const int*   det    = (const int*)d_in[2];
    const int*   cls    = (const int*)d_in[3];
    const float* conv_w = (const float*)d_in[4];
    const float* conv_b = (const float*)d_in[5];
    const float* w1     = (const float*)d_in[6];
    const float* b1     = (const float*)d_in[7];
    const float* w2p    = (const float*)d_in[8];
    const float* b2p    = (const float*)d_in[9];
    const float* w2a    = (const float*)d_in[10];
    const float* b2a    = (const float*)d_in[11];
    const float* w2ad   = (const float*)d_in[12];
    const float* b2ad   = (const float*)d_in[13];
    float* out = (float*)d_out;

    char* w = (char*)d_ws;
    unsigned short* flatbf = (unsigned short*)w;                    // 7,340,032 B
    unsigned short* BtW    = (unsigned short*)(w + 7340032);        // 1,048,576 B
    unsigned short* B2     = (unsigned short*)(w + 8388608);        //    98,304 B
    float*  bias2          = (float*)(w + 8486912);                 //     1,536 B
    float*  lse            = (float*)(w + 8488448);                 //   229,376 B
    float*  P              = (float*)(w + 8717824);                 // 12,546,072 B

    k_pre_cvt<<<3069 + 2240, 256, 0, stream>>>(x, w1, w2p, b2p, w2a, b2a, w2ad, b2ad,
                                               P, BtW, B2, bias2);
    k_extract<<<M_TOT, 256, 0, stream>>>(P, rois, conv_w, conv_b, flatbf);
    k_fc1_heads<<<dim3(56, 8), 256, 0, stream>>>(flatbf, BtW, b1, B2, bias2, out, lse);
    k_loss<<<28, 256, 0, stream>>>(lse, det, cls, out);
}

// Round 10
// 134.021 us; speedup vs baseline: 1.4608x; 1.1319x over previous
//
#include <hip/hip_runtime.h>

#define NROIS 1024
#define BANDS 7
#define M_TOT (NROIS*BANDS)        // 7168
#define ROI_W 224
#define BAND_H 16
#define FLATD 512
#define HD 1024                     // 8 heads * 128
#define PROV 38
#define ALPHA 25
#define ADC 35
#define NAD 6

#define OFF_A     (M_TOT*PROV)               // 272384
#define OFF_AD    (OFF_A + M_TOT*ALPHA)      // 451584
#define OFF_MASK  (OFF_AD + NAD*M_TOT*ADC)   // 1956864
#define OFF_TOTAL (OFF_MASK + M_TOT)         // 1964032

typedef __attribute__((ext_vector_type(4))) float f32x4;
typedef __attribute__((ext_vector_type(2))) float f32x2;
typedef __attribute__((ext_vector_type(8))) short bf16x8;

static __device__ __forceinline__ unsigned short f2bf(float f){
    union { float f; unsigned int u; } v; v.f = f;
    unsigned int u = v.u;
    unsigned int r = (u + 0x7fffu + ((u >> 16) & 1u)) >> 16;
    return (unsigned short)r;
}

// async global->LDS, 16B per lane, wave-uniform LDS base + lane*16
#define GL16(gp, lp) __builtin_amdgcn_global_load_lds( \
    (const __attribute__((address_space(1))) unsigned int*)(gp), \
    (__attribute__((address_space(3))) unsigned int*)(lp), 16, 0, 0)

// P2[c][row][s][q] = max over x[c][row..row+1][(14q+s)..(14q+s+13)]
#define P2ROW(c,row) (((size_t)((c)*1023 + (row)))*1022)

// ---------------- Kernel 0: fused precompute P2 + weight conversions
__global__ __launch_bounds__(256) void k_pre_cvt(
    const float* __restrict__ x, const float* __restrict__ w1,
    const float* __restrict__ w2p, const float* __restrict__ b2p,
    const float* __restrict__ w2a, const float* __restrict__ b2a,
    const float* __restrict__ w2ad, const float* __restrict__ b2ad,
    float* __restrict__ P, unsigned short* __restrict__ Bt,
    unsigned short* __restrict__ B2, float* __restrict__ bias2)
{
    __shared__ float v[1024];
    int blk = blockIdx.x;
    int t = threadIdx.x;
    if (blk < 3069){
        int c = blk / 1023, r = blk - c*1023;
        const float* row0 = x + ((size_t)c*1024 + r)*1024;
        const float* row1 = row0 + 1024;
        #pragma unroll
        for (int i=0;i<4;i++){
            int j = t + i*256;
            v[j] = fmaxf(row0[j], row1[j]);
        }
        __syncthreads();
        float* Pr = P + P2ROW(c, r);
        #pragma unroll
        for (int i=0;i<4;i++){
            int o = t + i*256;               // o = s*73 + q
            if (o < 1022){
                int s = o / 73, q = o - s*73;
                int j = 14*q + s;
                if (j < 1011){
                    float mv = v[j];
                    #pragma unroll
                    for (int d=1;d<14;d++) mv = fmaxf(mv, v[j+d]);
                    Pr[o] = mv;
                }
            }
        }
    } else {
        int i = (blk - 3069)*256 + t;
        if (i < 524288){
            int k = i >> 10, n = i & 1023;
            float val = w1[((size_t)(n>>7)*512 + k)*128 + (n&127)];
            Bt[(size_t)n*512 + k] = f2bf(val);
        } else {
            int j = i - 524288;          // < 49152
            int h = j / 6144;
            int rem = j - h*6144;
            int n = rem >> 7, k = rem & 127;
            float val = 0.f;
            if (h == 0){ if (n < 38) val = w2p[k*38 + n]; }
            else if (h == 1){ if (n < 25) val = w2a[k*25 + n]; }
            else { if (n < 35) val = w2ad[(size_t)(h-2)*128*35 + k*35 + n]; }
            B2[j] = f2bf(val);
            if (j < 8*48){
                int hh = j / 48, nn = j - hh*48;
                float bv = 0.f;
                if (hh == 0){ if (nn < 38) bv = b2p[nn]; }
                else if (hh == 1){ if (nn < 25) bv = b2a[nn]; }
                else { if (nn < 35) bv = b2ad[(hh-2)*35 + nn]; }
                bias2[j] = bv;
            }
        }
    }
}

// ---------------- Kernel 1: per-ROI block; 7 bands looped; weights in registers.
// thread t = (o2,p,q): o2=t>>5 handles out-channels o2 and o2+8 at position (p,q).
__global__ __launch_bounds__(256) void k_extract(
    const float* __restrict__ P, const int* __restrict__ rois,
    const float* __restrict__ conv_w, const float* __restrict__ conv_b,
    unsigned short* __restrict__ flat)
{
    __shared__ float pl[3][10][20];    // one band, zero border, stride 20 (8B-aligned pairs)
    __shared__ float cw[432];
    __shared__ float cb[16];

    int r = blockIdx.x;
    int t = threadIdx.x;
    int xx = rois[r*4+0];
    int y1 = rois[r*4+1];
    int sx = xx % 14, qx = xx / 14;
    int o2 = t >> 5, p = (t >> 3) & 3, q = t & 7;

    for (int i=t;i<432;i+=256) cw[i]=conv_w[i];
    if (t<16) cb[t]=conv_b[t];
    for (int i=t;i<3*10*20;i+=256) ((float*)pl)[i]=0.f;
    __syncthreads();

    // hoist both output-channels' weights + biases into registers
    float w[2][27];
    #pragma unroll
    for (int oi=0;oi<2;oi++){
        int o = o2 + oi*8;
        #pragma unroll
        for (int k=0;k<27;k++) w[oi][k] = cw[o*27 + k];
    }
    float bias0 = cb[o2], bias1 = cb[o2+8];

    for (int b=0; b<BANDS; b++){
        int yy = y1 + b*BAND_H;
        // gather pooled values for this band (coalesced 64B segments)
        for (int idx=t; idx<384; idx+=256){
            int c = idx>>7; int rem = idx&127; int ph = rem>>4; int pw = rem&15;
            pl[c][ph+1][pw+1] = P[P2ROW(c, yy + 2*ph) + (size_t)sx*73 + qx + pw];
        }
        __syncthreads();

        float s0[4] = {bias0,bias0,bias0,bias0};
        float s1[4] = {bias1,bias1,bias1,bias1};
        #pragma unroll
        for (int c=0;c<3;c++){
            float pt[4][4];
            #pragma unroll
            for (int di=0; di<4; di++){
                f32x2 a = *(const f32x2*)&pl[c][2*p+di][2*q];
                f32x2 bb = *(const f32x2*)&pl[c][2*p+di][2*q+2];
                pt[di][0]=a.x; pt[di][1]=a.y; pt[di][2]=bb.x; pt[di][3]=bb.y;
            }
            #pragma unroll
            for (int kh=0;kh<3;kh++)
              #pragma unroll
              for (int kw=0;kw<3;kw++){
                float w0 = w[0][c*9+kh*3+kw];
                float w1v = w[1][c*9+kh*3+kw];
                #pragma unroll
                for (int pos=0;pos<4;pos++){
                    float pv = pt[kh + (pos>>1)][kw + (pos&1)];
                    s0[pos] += pv*w0;
                    s1[pos] += pv*w1v;
                }
              }
        }
        float mx0 = fmaxf(fmaxf(fmaxf(s0[0],s0[1]), fmaxf(s0[2],s0[3])), 0.f);
        float mx1 = fmaxf(fmaxf(fmaxf(s1[0],s1[1]), fmaxf(s1[2],s1[3])), 0.f);
        size_t base = ((size_t)r*BANDS + b)*512;
        flat[base + t]       = f2bf(mx0);
        flat[base + t + 256] = f2bf(mx1);
        __syncthreads();
    }
}

// ---------------- Kernel 2: fused fc1 + heads + per-row LSE
// grid (56 m-tiles of 128, 8 heads), 256 threads (4 waves).
__global__ __launch_bounds__(256) void k_fc1_heads(
    const unsigned short* __restrict__ A, const unsigned short* __restrict__ Bt,
    const float* __restrict__ b1, const unsigned short* __restrict__ B2,
    const float* __restrict__ bias2, float* __restrict__ out,
    float* __restrict__ lse_ws)
{
    __shared__ short smem[16896];              // union: staging (16384) / Hl (16896)
    short* As = smem;                          // As[2][4096]
    short* Bs = smem + 8192;                   // Bs[2][4096]
    short* Hl = smem;                          // Hl[128][132]

    int bm = blockIdx.x, h = blockIdx.y;
    int m0 = bm*128;
    int t = threadIdx.x;
    int wid = t >> 6, lane = t & 63;
    int wr = wid >> 1, wc = wid & 1;
    int l15 = lane & 15, l4 = lane >> 4;

    if (bm == 0 && h == 0 && t == 0) out[OFF_TOTAL] = 0.f;

    const unsigned short* gA = A  + ((size_t)(m0    + wid*16 + (lane>>2)))*FLATD + (lane&3)*8;
    const unsigned short* gB = Bt + ((size_t)(h*128 + wid*16 + (lane>>2)))*FLATD + (lane&3)*8;

    f32x4 acc[4][4];
    #pragma unroll
    for (int i=0;i<4;i++)
      #pragma unroll
      for (int j=0;j<4;j++) acc[i][j] = (f32x4){0.f,0.f,0.f,0.f};

    GL16(gA,            As + wid*512);
    GL16(gA + 64*FLATD, As + 2048 + wid*512);
    GL16(gB,            Bs + wid*512);
    GL16(gB + 64*FLATD, Bs + 2048 + wid*512);
    __syncthreads();

    #pragma unroll
    for (int ks=0; ks<16; ks++){
        int cur = ks & 1;
        if (ks < 15){
            int k1 = (ks+1)*32;
            int nb = (cur^1)*4096;
            GL16(gA + k1,            As + nb + wid*512);
            GL16(gA + 64*FLATD + k1, As + nb + 2048 + wid*512);
            GL16(gB + k1,            Bs + nb + wid*512);
            GL16(gB + 64*FLATD + k1, Bs + nb + 2048 + wid*512);
        }
        bf16x8 af[4], bfv[4];
        #pragma unroll
        for (int mf=0;mf<4;mf++) af[mf]  = *(const bf16x8*)&As[cur*4096 + (wr*64 + mf*16 + l15)*32 + l4*8];
        #pragma unroll
        for (int nf=0;nf<4;nf++) bfv[nf] = *(const bf16x8*)&Bs[cur*4096 + (wc*64 + nf*16 + l15)*32 + l4*8];
        #pragma unroll
        for (int mf=0;mf<4;mf++)
          #pragma unroll
          for (int nf=0;nf<4;nf++)
            acc[mf][nf] = __builtin_amdgcn_mfma_f32_16x16x32_bf16(af[mf], bfv[nf], acc[mf][nf], 0, 0, 0);
        __syncthreads();
    }

    // Phase 2a: H tile -> LDS (bf16, bias+relu applied)
    #pragma unroll
    for (int nf=0;nf<4;nf++){
        int col = wc*64 + nf*16 + l15;
        float bias = b1[h*128 + col];
        #pragma unroll
        for (int mf=0;mf<4;mf++){
            #pragma unroll
            for (int reg=0;reg<4;reg++){
                int row = wr*64 + mf*16 + l4*4 + reg;
                Hl[row*132 + col] = (short)f2bf(fmaxf(acc[mf][nf][reg] + bias, 0.f));
            }
        }
    }
    __syncthreads();

    // Phase 2b: logits = H_tile @ W2[head]
    f32x4 acc2[2][3];
    #pragma unroll
    for (int i=0;i<2;i++)
      #pragma unroll
      for (int j=0;j<3;j++) acc2[i][j] = (f32x4){0.f,0.f,0.f,0.f};

    const unsigned short* Bh = B2 + (size_t)h*6144;
    #pragma unroll
    for (int ks=0; ks<4; ks++){
        bf16x8 ha[2], hb[3];
        #pragma unroll
        for (int m2=0;m2<2;m2++)
            ha[m2] = *(const bf16x8*)&Hl[(wid*32 + m2*16 + l15)*132 + ks*32 + l4*8];
        #pragma unroll
        for (int nf=0;nf<3;nf++)
            hb[nf] = *(const bf16x8*)(Bh + (nf*16 + l15)*128 + ks*32 + l4*8);
        #pragma unroll
        for (int m2=0;m2<2;m2++)
          #pragma unroll
          for (int nf=0;nf<3;nf++)
            acc2[m2][nf] = __builtin_amdgcn_mfma_f32_16x16x32_bf16(ha[m2], hb[nf], acc2[m2][nf], 0, 0, 0);
    }

    int Nh = (h==0) ? 38 : ((h==1) ? 25 : 35);
    #pragma unroll
    for (int nf=0;nf<3;nf++){
        int col = nf*16 + l15;
        float bv = bias2[h*48 + col];
        #pragma unroll
        for (int m2=0;m2<2;m2++){
            #pragma unroll
            for (int reg=0;reg<4;reg++){
                acc2[m2][nf][reg] += bv;
                if (col < Nh){
                    int m = m0 + wid*32 + m2*16 + l4*4 + reg;
                    size_t a;
                    if (h == 0)      a = (size_t)m*38 + col;
                    else if (h == 1) a = OFF_A + (size_t)m*25 + col;
                    else             a = OFF_AD + ((size_t)(h-2)*M_TOT + m)*35 + col;
                    out[a] = acc2[m2][nf][reg];
                }
            }
        }
    }

    // Phase 2c: per-row LSE via 16-lane shfl reduce
    #pragma unroll
    for (int m2=0;m2<2;m2++){
        #pragma unroll
        for (int reg=0;reg<4;reg++){
            float mx = -1e30f;
            #pragma unroll
            for (int nf=0;nf<3;nf++){
                int col = nf*16 + l15;
                if (col < Nh) mx = fmaxf(mx, acc2[m2][nf][reg]);
            }
            #pragma unroll
            for (int d=1; d<16; d<<=1) mx = fmaxf(mx, __shfl_xor(mx, d));
            float s = 0.f;
            #pragma unroll
            for (int nf=0;nf<3;nf++){
                int col = nf*16 + l15;
                if (col < Nh) s += __expf(acc2[m2][nf][reg] - mx);
            }
            #pragma unroll
            for (int d=1; d<16; d<<=1) s += __shfl_xor(s, d);
            if (l15 == 0){
                int m = m0 + wid*32 + m2*16 + l4*4 + reg;
                lse_ws[(size_t)m*8 + h] = mx + __logf(s);
            }
        }
    }
}

// ---------------- Kernel 3: per-row losses + mask + total
__global__ __launch_bounds__(256) void k_loss(
    const float* __restrict__ lse_ws, const int* __restrict__ det_t,
    const int* __restrict__ cls_t, float* __restrict__ out)
{
    int m = blockIdx.x*256 + threadIdx.x;
    if (m >= M_TOT) return;
    int r = m / 7;
    const float* L = lse_ws + (size_t)m*8;
    float det_loss = L[0] - out[(size_t)m*38 + det_t[r]];
    bool mk = det_loss < 0.25f;
    out[OFF_MASK + m] = mk ? 1.f : 0.f;
    if (mk){
        const int* ct = cls_t + r*8;
        float c = (L[0] - out[(size_t)m*38 + ct[0]]) + (L[1] - out[OFF_A + (size_t)m*25 + ct[1]]);
        #pragma unroll
        for (int j=0;j<6;j++)
            c += L[2+j] - out[OFF_AD + ((size_t)j*M_TOT + m)*35 + ct[2+j]];
        atomicAdd(out + OFF_TOTAL, c);
    }
}

extern "C" void kernel_launch(void* const* d_in, const int* in_sizes, int n_in,
                              void* d_out, int out_size, void* d_ws, size_t ws_size,
                              hipStream_t stream) {
    const float* x      = (const float*)d_in[0];
    const int*   rois   = (const int*)d_in[1];
    const int*   det    = (const int*)d_in[2];
    const int*   cls    = (const int*)d_in[3];
    const float* conv_w = (const float*)d_in[4];
    const float* conv_b = (const float*)d_in[5];
    const float* w1     = (const float*)d_in[6];
    const float* b1     = (const float*)d_in[7];
    const float* w2p    = (const float*)d_in[8];
    const float* b2p    = (const float*)d_in[9];
    const float* w2a    = (const float*)d_in[10];
    const float* b2a    = (const float*)d_in[11];
    const float* w2ad   = (const float*)d_in[12];
    const float* b2ad   = (const float*)d_in[13];
    float* out = (float*)d_out;

    char* w = (char*)d_ws;
    unsigned short* flatbf = (unsigned short*)w;                    // 7,340,032 B
    unsigned short* BtW    = (unsigned short*)(w + 7340032);        // 1,048,576 B
    unsigned short* B2     = (unsigned short*)(w + 8388608);        //    98,304 B
    float*  bias2          = (float*)(w + 8486912);                 //     1,536 B
    float*  lse            = (float*)(w + 8488448);                 //   229,376 B
    float*  P              = (float*)(w + 8717824);                 // 12,546,072 B

    k_pre_cvt<<<3069 + 2240, 256, 0, stream>>>(x, w1, w2p, b2p, w2a, b2a, w2ad, b2ad,
                                               P, BtW, B2, bias2);
    k_extract<<<NROIS, 256, 0, stream>>>(P, rois, conv_w, conv_b, flatbf);
    k_fc1_heads<<<dim3(56, 8), 256, 0, stream>>>(flatbf, BtW, b1, B2, bias2, out, lse);
    k_loss<<<28, 256, 0, stream>>>(lse, det, cls, out);
}